// Round 10
// baseline (1173.424 us; speedup 1.0000x reference)
//
#include <hip/hip_runtime.h>
#include <hip/hip_bf16.h>
#include <math.h>

// Problem constants
#define Bz 4
#define Vz 2048
#define RA 40   // R*A = 5*8

typedef short bf16x8 __attribute__((ext_vector_type(8)));
typedef float f32x4 __attribute__((ext_vector_type(4)));

__device__ __forceinline__ unsigned fasu(float f){ union{float f;unsigned u;}x;x.f=f;return x.u; }
__device__ __forceinline__ float usaf(unsigned u){ union{unsigned u;float f;}x;x.u=u;return x.f; }

// fp32 -> bf16 RNE (weight split, done once per layer)
__device__ __forceinline__ unsigned short f2bf(float f) {
    unsigned u = fasu(f);
    unsigned r = u + 0x7FFF + ((u >> 16) & 1);
    return (unsigned short)(r >> 16);
}
__device__ __forceinline__ float bf2f(unsigned short h) { return usaf(((unsigned)h) << 16); }

__constant__ float NORM_MEAN_C[30] = {
    -3.7189561e-06f, 0.000286194f, 0.0020740835f, 6.5275993f, -0.0052857199f,
    10.554636f, 0.057773598f, 13.915789f, 0.060970016f, 16.840271f,
    0.0570364f, 19.415283f, 0.044104282f, 21.721455f, 0.11490919f,
    23.64683f, 0.099816084f, 25.365578f, 0.01769533f, 26.861437f,
    0.054662503f, 28.197876f, -0.0024771576f, 29.295244f, 0.039666731f,
    30.319246f, 0.0088442909f, 31.160933f, -0.026727753f, 31.874565f};
__constant__ float NORM_VAR_C[30] = {
    3.3091978e-06f, 0.00016750646f, 0.80988622f, 85135.219f, 1.5621265f,
    222580.2f, 8.812871f, 386912.78f, 10.180468f, 566622.44f,
    9.8600769f, 753158.06f, 7.8372045f, 942701.62f, 30.926426f,
    1117233.0f, 25.045353f, 1285543.9f, 6.3646226f, 1441639.1f,
    12.326629f, 1588653.4f, 6.9686499f, 1714707.9f, 10.755516f,
    1836677.8f, 8.416419f, 1940088.8f, 10.344138f, 2029969.6f};

__device__ __forceinline__ float elu_f(float x) {
    return x > 0.f ? x : expm1f(x);
}

// x0[b,v,c] = (signal - mean[c]) * rsqrt(var[c])
__global__ void norm_kernel(const float* __restrict__ sig, float* __restrict__ x0) {
    int e = blockIdx.x * 256 + threadIdx.x;
    if (e >= Bz * Vz * 30) return;
    int c = e % 30;
    x0[e] = (sig[e] - NORM_MEAN_C[c]) * rsqrtf(NORM_VAR_C[c]);
}

// Weight expand (no rotation; rotations live in M). Split-bf16, fragment-linear:
// per (kb,plane): off = (n>>4)*512 + (kk>>3)*128 + (n&15)*8 + (kk&7)
template <int CROW, int T, int KB>
__global__ void expand_wt(const float* __restrict__ kern, unsigned short* __restrict__ wt) {
    int e = blockIdx.x * 256 + threadIdx.x;
    if (e >= KB * T * 32) return;
    int kb = e / (T * 32);
    int rem = e % (T * 32);
    int n = rem >> 5, kk = rem & 31;
    int ra, c;
    if (CROW == 128) { ra = kb >> 2; c = (kb & 3) * 32 + kk; }
    else             { ra = kb;      c = kk; }
    float v = (c < CROW) ? kern[((size_t)(ra * T + n)) * CROW + c] : 0.f;
    unsigned short hi = f2bf(v);
    unsigned short lo = f2bf(v - bf2f(hi));
    size_t off = ((size_t)kb * 2) * T * 32 + (n >> 4) * 512 + (kk >> 3) * 128 + (n & 15) * 8 + (kk & 7);
    wt[off] = hi;
    wt[off + (size_t)T * 32] = lo;
}

// Precompute split-bf16 interp tensor, rotation-contiguous layout:
// I[v][r][cb][plane][ag][32c]; element off =
//   (((v*5 + r)*CBn + cb)*2 + plane)*256 + ag*32 + c
// VS vertices in this slice (voff = first global vertex). Thread handles 8 c.
template <int CROW, int CBn, int VS>
__global__ void interp_i(const float* __restrict__ x, const int* __restrict__ idxg,
                         const float* __restrict__ wg, unsigned short* __restrict__ I,
                         int voff) {
    constexpr int UNITS = 5 * CBn * 32;   // q-threads per vertex
    int e = blockIdx.x * 256 + threadIdx.x;
    if (e >= VS * UNITS) return;
    int v = e / UNITS;
    int rem = e % UNITS;
    int r = rem / (CBn * 32);
    int rem2 = rem % (CBn * 32);
    int cb = rem2 >> 5;
    int ag = (rem2 >> 2) & 7;
    int q = rem2 & 3;
    int gv = voff + v;
    int b = gv >> 11;
    size_t gi = ((size_t)gv * RA + (r * 8 + ag)) * 3;
    int i0 = idxg[gi], i1 = idxg[gi + 1], i2 = idxg[gi + 2];
    float w0 = wg[gi], w1 = wg[gi + 1], w2 = wg[gi + 2];
    const float* x0 = x + ((size_t)(b << 11) + i0) * CROW;
    const float* x1 = x + ((size_t)(b << 11) + i1) * CROW;
    const float* x2 = x + ((size_t)(b << 11) + i2) * CROW;
    const int c0 = cb * 32 + q * 8;
    float vv[8];
    if (CROW == 128) {
        const float4* q0 = (const float4*)(x0 + c0);
        const float4* q1 = (const float4*)(x1 + c0);
        const float4* q2 = (const float4*)(x2 + c0);
#pragma unroll
        for (int qq = 0; qq < 2; ++qq) {
            float4 a4 = q0[qq], b4 = q1[qq], c4 = q2[qq];
            vv[qq * 4 + 0] = w0 * a4.x + w1 * b4.x + w2 * c4.x;
            vv[qq * 4 + 1] = w0 * a4.y + w1 * b4.y + w2 * c4.y;
            vv[qq * 4 + 2] = w0 * a4.z + w1 * b4.z + w2 * c4.z;
            vv[qq * 4 + 3] = w0 * a4.w + w1 * b4.w + w2 * c4.w;
        }
    } else {
#pragma unroll
        for (int j = 0; j < 8; ++j) {
            int c = c0 + j;
            vv[j] = (c < CROW) ? (w0 * x0[c] + w1 * x1[c] + w2 * x2[c]) : 0.f;
        }
    }
    unsigned hiw[4], low_[4];
#pragma unroll
    for (int p = 0; p < 4; ++p) {
        float v0 = vv[2 * p], v1 = vv[2 * p + 1];
        unsigned u0 = fasu(v0), u1 = fasu(v1);
        unsigned h0 = u0 & 0xFFFF0000u, h1 = u1 & 0xFFFF0000u;
        float l0 = v0 - usaf(h0), l1 = v1 - usaf(h1);
        hiw[p] = (u0 >> 16) | h1;
        low_[p] = (fasu(l0) >> 16) | (fasu(l1) & 0xFFFF0000u);
    }
    size_t off = ((((size_t)v * 5 + r) * CBn + cb) * 2) * 256 + ag * 32 + q * 8;
    *(uint4*)&I[off]       = make_uint4(hiw[0], hiw[1], hiw[2], hiw[3]);
    *(uint4*)&I[off + 256] = make_uint4(low_[0], low_[1], low_[2], low_[3]);
}

// Barrier-free fused conv GEMM from precomputed I. Rows m = (slice v)*8 + o,
// BM=128 (16 v x 8 o), BN = T, NW n-waves (2 -> 256 thr, 4 -> 512 thr), wave
// tile 64x64. A-frags: dense 16B/lane global loads, rotation via ag=(a'+fro)&7
// in the address; B-frags global->VGPR (L2-hot). No LDS staging, no K-loop
// barriers -> compiler pipelines loads across steps with fine vmcnt.
// Epilogue: elu+bias, row norms, AMP argmax over 8 rotations, BN, write xout.
template <int CBn, int T, int NW>
__global__ __launch_bounds__(128 * NW) void gemm_f(const unsigned short* __restrict__ I,
                                                   const unsigned short* __restrict__ wt,
                                                   const float* __restrict__ bias,
                                                   const float* __restrict__ g,
                                                   const float* __restrict__ be,
                                                   float* __restrict__ xout, int voff) {
    constexpr int VST = 5 * CBn * 512;   // I elements per vertex
    __shared__ float normp[128][NW];
    __shared__ int bo[16];
    const int tid = threadIdx.x;
    const int wid = tid >> 6, lane = tid & 63;
    const int fr = lane & 15, fq = lane >> 4;
    const int fro = fr & 7, frv = fr >> 3;
    const int wm = (wid & 1) * 64, wn = (wid >> 1) * 64;
    const int m0 = blockIdx.y * 128;
    const int nbase = wn >> 4;
    const int vb = (m0 >> 3) + (wm >> 3);
    const unsigned short* abase = I + (size_t)(vb + frv) * VST + fq * 8;
    const unsigned short* bwave = wt + nbase * 512 + lane * 8;

    f32x4 acc[4][4] = {};

    for (int r = 0; r < 5; ++r)
        for (int cb = 0; cb < CBn; ++cb) {
            const unsigned short* awin = abase + (r * CBn + cb) * 512;
#pragma unroll
            for (int ap = 0; ap < 8; ++ap) {
                const int kbw = (r * 8 + ap) * CBn + cb;
                const unsigned short* bp = bwave + (size_t)kbw * (T * 64);
                bf16x8 bh[4], bl[4];
#pragma unroll
                for (int nj = 0; nj < 4; ++nj) {
                    bh[nj] = *(const bf16x8*)(bp + nj * 512);
                    bl[nj] = *(const bf16x8*)(bp + (size_t)T * 32 + nj * 512);
                }
                const int ag = (ap + fro) & 7;
                const unsigned short* apt = awin + ag * 32;
                bf16x8 ah[4], alo[4];
#pragma unroll
                for (int mi = 0; mi < 4; ++mi) {
                    ah[mi]  = *(const bf16x8*)(apt + mi * 2 * VST);
                    alo[mi] = *(const bf16x8*)(apt + mi * 2 * VST + 256);
                }
#pragma unroll
                for (int mi = 0; mi < 4; ++mi)
#pragma unroll
                    for (int nj = 0; nj < 4; ++nj) {
                        acc[mi][nj] = __builtin_amdgcn_mfma_f32_16x16x32_bf16(ah[mi],  bh[nj], acc[mi][nj], 0, 0, 0);
                        acc[mi][nj] = __builtin_amdgcn_mfma_f32_16x16x32_bf16(ah[mi],  bl[nj], acc[mi][nj], 0, 0, 0);
                        acc[mi][nj] = __builtin_amdgcn_mfma_f32_16x16x32_bf16(alo[mi], bh[nj], acc[mi][nj], 0, 0, 0);
                    }
            }
        }

    // ---- fused epilogue: elu+bias, AMP argmax, BN, write ----
    float ss[4][4];
#pragma unroll
    for (int mi = 0; mi < 4; ++mi)
#pragma unroll
        for (int rr = 0; rr < 4; ++rr) ss[mi][rr] = 0.f;
#pragma unroll
    for (int mi = 0; mi < 4; ++mi)
#pragma unroll
        for (int nj = 0; nj < 4; ++nj)
#pragma unroll
            for (int rr = 0; rr < 4; ++rr) {
                float val = elu_f(acc[mi][nj][rr] + bias[wn + nj * 16 + fr]);
                acc[mi][nj][rr] = val;
                ss[mi][rr] += val * val;
            }
#pragma unroll
    for (int mi = 0; mi < 4; ++mi)
#pragma unroll
        for (int rr = 0; rr < 4; ++rr) {
            float s = ss[mi][rr];
            s += __shfl_xor(s, 1); s += __shfl_xor(s, 2);
            s += __shfl_xor(s, 4); s += __shfl_xor(s, 8);
            if (fr == 0) normp[wm + mi * 16 + fq * 4 + rr][wn >> 6] = s;
        }
    __syncthreads();
    if (tid < 16) {
        float best = -1.f; int bsel = 0;
#pragma unroll
        for (int oo = 0; oo < 8; ++oo) {
            float tot = 0.f;
#pragma unroll
            for (int wnn = 0; wnn < NW; ++wnn) tot += normp[tid * 8 + oo][wnn];
            if (tot > best) { best = tot; bsel = oo; }   // first max wins
        }
        bo[tid] = bsel;
    }
    __syncthreads();
    const float rsbn = rsqrtf(1.001f);
#pragma unroll
    for (int mi = 0; mi < 4; ++mi)
#pragma unroll
        for (int rr = 0; rr < 4; ++rr) {
            int row = wm + mi * 16 + fq * 4 + rr;
            if ((row & 7) == bo[row >> 3]) {
                int vg = voff + (m0 >> 3) + (row >> 3);
#pragma unroll
                for (int nj = 0; nj < 4; ++nj) {
                    int n = wn + nj * 16 + fr;
                    xout[(size_t)vg * T + n] = acc[mi][nj][rr] * g[n] * rsbn + be[n];
                }
            }
        }
}

// ---------------- Layer-1 kernel: round-6 version verbatim (in-kernel I-build,
// one barrier/group, B frags global->VGPR). Best measured config for L1. ------
template <int CROW>
__device__ __forceinline__ void build_vv_scalar(float* vv, const float* xb_,
                                                int i0, int i1, int i2,
                                                float w0, float w1, float w2, int cs) {
    const float* q0 = xb_ + (size_t)i0 * CROW;
    const float* q1 = xb_ + (size_t)i1 * CROW;
    const float* q2 = xb_ + (size_t)i2 * CROW;
#pragma unroll
    for (int j = 0; j < 16; ++j) {
        int c = cs + j;
        vv[j] = (c < CROW) ? (w0 * q0[c] + w1 * q1[c] + w2 * q2[c]) : 0.f;
    }
}

template <int CROW, int T, int KB, bool FUSE>
__global__ __launch_bounds__(256) void conv_k(const float* __restrict__ x,
                                              const int* __restrict__ bc_idx,
                                              const float* __restrict__ bc_w,
                                              const unsigned short* __restrict__ wt,
                                              const float* __restrict__ bias,
                                              const float* __restrict__ g,
                                              const float* __restrict__ be,
                                              float* __restrict__ xout) {
    constexpr int CB = (CROW == 128) ? 4 : 1;
    constexpr int G = KB / 8;
    __shared__ unsigned short Ih[2][4096], Il[2][4096];
    __shared__ float normp[128][2];
    __shared__ int bo[16];
    const int tid = threadIdx.x;
    const int wid = tid >> 6, lane = tid & 63;
    const int fr = lane & 15, fq = lane >> 4;
    const int fro = fr & 7, frv = fr & 8;
    const int wm = (wid & 1) * 64, wn = (wid >> 1) * 64;
    const int bn = blockIdx.x * 128;
    const int m0 = blockIdx.y * 128;
    const int b = m0 >> 14;
    const float* xb_ = x + (size_t)b * Vz * CROW;
    const int* idxb = bc_idx + (size_t)b * Vz * RA * 3;
    const float* wb = bc_w + (size_t)b * Vz * RA * 3;

    const int rloc = tid >> 1;
    const int chalf = tid & 1;
    const int aI = rloc & 7;
    const int vglob_b = ((m0 & 16383) >> 3) + (rloc >> 3);
    const int offA = (rloc >> 4) * 512 + chalf * 256 + (rloc & 15) * 8;
    const int ibase = (wm >> 4) * 512 + fq * 128 + frv * 8;
    const int nbase = (bn + wn) >> 4;

    f32x4 acc[4][4] = {};

    auto split_write = [&](const float* vv, int buf) {
        unsigned hiw[8], low_[8];
#pragma unroll
        for (int p = 0; p < 8; ++p) {
            float v0 = vv[2 * p], v1 = vv[2 * p + 1];
            unsigned u0 = fasu(v0), u1 = fasu(v1);
            unsigned h0 = u0 & 0xFFFF0000u, h1 = u1 & 0xFFFF0000u;
            float l0 = v0 - usaf(h0), l1 = v1 - usaf(h1);
            hiw[p] = (u0 >> 16) | h1;
            low_[p] = (fasu(l0) >> 16) | (fasu(l1) & 0xFFFF0000u);
        }
        *(uint4*)&Ih[buf][offA]       = make_uint4(hiw[0], hiw[1], hiw[2], hiw[3]);
        *(uint4*)&Ih[buf][offA + 128] = make_uint4(hiw[4], hiw[5], hiw[6], hiw[7]);
        *(uint4*)&Il[buf][offA]       = make_uint4(low_[0], low_[1], low_[2], low_[3]);
        *(uint4*)&Il[buf][offA + 128] = make_uint4(low_[4], low_[5], low_[6], low_[7]);
    };

    int i_n0 = 0, i_n1 = 0, i_n2 = 0; float w_n0 = 0.f, w_n1 = 0.f, w_n2 = 0.f;
    {
        const int gi = (vglob_b * RA + aI) * 3;
        int a0 = idxb[gi], a1 = idxb[gi + 1], a2 = idxb[gi + 2];
        float b0_ = wb[gi], b1_ = wb[gi + 1], b2_ = wb[gi + 2];
        float vv[16];
        const int cs0 = chalf * 16;
        if (CROW == 128) {
            const float4* q0 = (const float4*)(xb_ + (size_t)a0 * CROW + cs0);
            const float4* q1 = (const float4*)(xb_ + (size_t)a1 * CROW + cs0);
            const float4* q2 = (const float4*)(xb_ + (size_t)a2 * CROW + cs0);
#pragma unroll
            for (int qq = 0; qq < 4; ++qq) {
                float4 a4 = q0[qq], b4 = q1[qq], c4 = q2[qq];
                vv[qq * 4 + 0] = b0_ * a4.x + b1_ * b4.x + b2_ * c4.x;
                vv[qq * 4 + 1] = b0_ * a4.y + b1_ * b4.y + b2_ * c4.y;
                vv[qq * 4 + 2] = b0_ * a4.z + b1_ * b4.z + b2_ * c4.z;
                vv[qq * 4 + 3] = b0_ * a4.w + b1_ * b4.w + b2_ * c4.w;
            }
        } else {
            build_vv_scalar<CROW>(vv, xb_, a0, a1, a2, b0_, b1_, b2_, cs0);
        }
        split_write(vv, 0);
        if (G > 1) {
            const int rn = 1 / CB;
            const int gi2 = (vglob_b * RA + rn * 8 + aI) * 3;
            i_n0 = idxb[gi2]; i_n1 = idxb[gi2 + 1]; i_n2 = idxb[gi2 + 2];
            w_n0 = wb[gi2];   w_n1 = wb[gi2 + 1];   w_n2 = wb[gi2 + 2];
        }
    }
    __syncthreads();

    for (int gidx = 0; gidx < G; ++gidx) {
        const bool hn = (gidx + 1 < G);
        const int ni0 = i_n0, ni1 = i_n1, ni2 = i_n2;
        const float nw0 = w_n0, nw1 = w_n1, nw2 = w_n2;
        const int cs_n = ((gidx + 1) % CB) * 32 + chalf * 16;

        float4 qr0[4], qr1[4], qr2[4];
        float gq0[16], gq1[16], gq2[16];
        if (hn) {
            if (CROW == 128) {
                const float4* q0 = (const float4*)(xb_ + (size_t)ni0 * CROW + cs_n);
                const float4* q1 = (const float4*)(xb_ + (size_t)ni1 * CROW + cs_n);
                const float4* q2 = (const float4*)(xb_ + (size_t)ni2 * CROW + cs_n);
#pragma unroll
                for (int qq = 0; qq < 4; ++qq) { qr0[qq] = q0[qq]; qr1[qq] = q1[qq]; qr2[qq] = q2[qq]; }
            } else {
                const float* q0 = xb_ + (size_t)ni0 * CROW;
                const float* q1 = xb_ + (size_t)ni1 * CROW;
                const float* q2 = xb_ + (size_t)ni2 * CROW;
#pragma unroll
                for (int j = 0; j < 16; ++j) {
                    int c = cs_n + j;
                    bool ok = (c < CROW);
                    gq0[j] = ok ? q0[c] : 0.f;
                    gq1[j] = ok ? q1[c] : 0.f;
                    gq2[j] = ok ? q2[c] : 0.f;
                }
            }
        }
        if (gidx + 2 < G) {
            const int rn = (gidx + 2) / CB;
            const int gi = (vglob_b * RA + rn * 8 + aI) * 3;
            i_n0 = idxb[gi]; i_n1 = idxb[gi + 1]; i_n2 = idxb[gi + 2];
            w_n0 = wb[gi];   w_n1 = wb[gi + 1];   w_n2 = wb[gi + 2];
        }

        const int r8 = (gidx / CB) * 8;
        const int cbg = gidx % CB;
        const int ibuf = gidx & 1;
#pragma unroll
        for (int ap = 0; ap < 8; ++ap) {
            const int kb = (CROW == 128) ? ((r8 + ap) * 4 + cbg) : (r8 + ap);
            const unsigned short* bb = wt + ((size_t)kb * 2) * (T * 32) +
                                       (size_t)nbase * 512 + lane * 8;
            bf16x8 bh[4], bl[4];
#pragma unroll
            for (int nj = 0; nj < 4; ++nj) {
                bh[nj] = *(const bf16x8*)(bb + nj * 512);
                bl[nj] = *(const bf16x8*)(bb + (size_t)T * 32 + nj * 512);
            }
            const int rot = (ap + fro) & 7;
            bf16x8 ah[4], al[4];
#pragma unroll
            for (int mi = 0; mi < 4; ++mi) {
                const int ad = ibase + mi * 512 + rot * 8;
                ah[mi] = *(const bf16x8*)&Ih[ibuf][ad];
                al[mi] = *(const bf16x8*)&Il[ibuf][ad];
            }
#pragma unroll
            for (int mi = 0; mi < 4; ++mi)
#pragma unroll
                for (int nj = 0; nj < 4; ++nj) {
                    acc[mi][nj] = __builtin_amdgcn_mfma_f32_16x16x32_bf16(ah[mi], bh[nj], acc[mi][nj], 0, 0, 0);
                    acc[mi][nj] = __builtin_amdgcn_mfma_f32_16x16x32_bf16(ah[mi], bl[nj], acc[mi][nj], 0, 0, 0);
                    acc[mi][nj] = __builtin_amdgcn_mfma_f32_16x16x32_bf16(al[mi], bh[nj], acc[mi][nj], 0, 0, 0);
                }
        }

        if (hn) {
            float vv[16];
            if (CROW == 128) {
#pragma unroll
                for (int qq = 0; qq < 4; ++qq) {
                    float4 a4 = qr0[qq], b4 = qr1[qq], c4 = qr2[qq];
                    vv[qq * 4 + 0] = nw0 * a4.x + nw1 * b4.x + nw2 * c4.x;
                    vv[qq * 4 + 1] = nw0 * a4.y + nw1 * b4.y + nw2 * c4.y;
                    vv[qq * 4 + 2] = nw0 * a4.z + nw1 * b4.z + nw2 * c4.z;
                    vv[qq * 4 + 3] = nw0 * a4.w + nw1 * b4.w + nw2 * c4.w;
                }
            } else {
#pragma unroll
                for (int j = 0; j < 16; ++j)
                    vv[j] = nw0 * gq0[j] + nw1 * gq1[j] + nw2 * gq2[j];
            }
            split_write(vv, (gidx + 1) & 1);
        }
        __syncthreads();
    }

    if (FUSE) {
        float ss[4][4];
#pragma unroll
        for (int mi = 0; mi < 4; ++mi)
#pragma unroll
            for (int r = 0; r < 4; ++r) ss[mi][r] = 0.f;
#pragma unroll
        for (int mi = 0; mi < 4; ++mi)
#pragma unroll
            for (int nj = 0; nj < 4; ++nj)
#pragma unroll
                for (int r = 0; r < 4; ++r) {
                    float val = elu_f(acc[mi][nj][r] + bias[bn + wn + nj * 16 + fr]);
                    acc[mi][nj][r] = val;
                    ss[mi][r] += val * val;
                }
#pragma unroll
        for (int mi = 0; mi < 4; ++mi)
#pragma unroll
            for (int r = 0; r < 4; ++r) {
                float s = ss[mi][r];
                s += __shfl_xor(s, 1); s += __shfl_xor(s, 2);
                s += __shfl_xor(s, 4); s += __shfl_xor(s, 8);
                if (fr == 0) normp[wm + mi * 16 + fq * 4 + r][wn >> 6] = s;
            }
        __syncthreads();
        if (tid < 16) {
            float best = -1.f; int bsel = 0;
#pragma unroll
            for (int oo = 0; oo < 8; ++oo) {
                float tot = normp[tid * 8 + oo][0] + normp[tid * 8 + oo][1];
                if (tot > best) { best = tot; bsel = oo; }
            }
            bo[tid] = bsel;
        }
        __syncthreads();
        const float rsbn = rsqrtf(1.001f);
#pragma unroll
        for (int mi = 0; mi < 4; ++mi)
#pragma unroll
            for (int r = 0; r < 4; ++r) {
                int row = wm + mi * 16 + fq * 4 + r;
                if ((row & 7) == bo[row >> 3]) {
                    int vg = (m0 >> 3) + (row >> 3);
#pragma unroll
                    for (int nj = 0; nj < 4; ++nj) {
                        int t = bn + wn + nj * 16 + fr;
                        xout[(size_t)vg * T + t] = acc[mi][nj][r] * g[t] * rsbn + be[t];
                    }
                }
            }
    }
}

// Global max pool stage 1. x: [B][V][256] -> partial [B*8][256]
__global__ void pool1(const float* __restrict__ x, float* __restrict__ partial) {
    int b = blockIdx.x >> 3, ch = blockIdx.x & 7, t = threadIdx.x;
    float m = -INFINITY;
    for (int i = 0; i < 256; ++i) {
        int v = ch * 256 + i;
        m = fmaxf(m, x[((size_t)b * Vz + v) * 256 + t]);
    }
    partial[(size_t)blockIdx.x * 256 + t] = m;
}

// Fused head: finish max-pool + 3-layer MLP. One block per batch.
__global__ __launch_bounds__(256) void head_k(const float* __restrict__ partial,
                                              const float* __restrict__ w1, const float* __restrict__ c1,
                                              const float* __restrict__ w2, const float* __restrict__ c2,
                                              const float* __restrict__ w3, const float* __restrict__ c3,
                                              float* __restrict__ outp) {
    __shared__ float p[256], h1s[512], h2s[256];
    const int b = blockIdx.x, tid = threadIdx.x;
    float m = -INFINITY;
#pragma unroll
    for (int ch = 0; ch < 8; ++ch)
        m = fmaxf(m, partial[((size_t)b * 8 + ch) * 256 + tid]);
    p[tid] = m;
    __syncthreads();
#pragma unroll
    for (int rep = 0; rep < 2; ++rep) {
        int n = rep * 256 + tid;
        float s = c1[n];
        for (int k = 0; k < 256; ++k) s += p[k] * w1[k * 512 + n];
        h1s[n] = elu_f(s);
    }
    __syncthreads();
    {
        float s = c2[tid];
        for (int k = 0; k < 512; ++k) s += h1s[k] * w2[k * 256 + tid];
        h2s[tid] = elu_f(s);
    }
    __syncthreads();
    if (tid < 40) {
        float s = c3[tid];
        for (int k = 0; k < 256; ++k) s += h2s[k] * w3[k * 40 + tid];
        outp[b * 40 + tid] = s;
    }
}

extern "C" void kernel_launch(void* const* d_in, const int* in_sizes, int n_in,
                              void* d_out, int out_size, void* d_ws, size_t ws_size,
                              hipStream_t stream) {
    const float* signal = (const float*)d_in[0];
    const int* bc_idx = (const int*)d_in[1];
    const float* bc_w = (const float*)d_in[2];
    const float* k0 = (const float*)d_in[3];
    const float* b0 = (const float*)d_in[4];
    const float* g0 = (const float*)d_in[5];
    const float* be0 = (const float*)d_in[6];
    const float* k1 = (const float*)d_in[7];
    const float* b1 = (const float*)d_in[8];
    const float* g1 = (const float*)d_in[9];
    const float* be1 = (const float*)d_in[10];
    const float* k2 = (const float*)d_in[11];
    const float* b2 = (const float*)d_in[12];
    const float* g2 = (const float*)d_in[13];
    const float* be2 = (const float*)d_in[14];
    const float* w1 = (const float*)d_in[15];
    const float* c1 = (const float*)d_in[16];
    const float* w2 = (const float*)d_in[17];
    const float* c2 = (const float*)d_in[18];
    const float* w3 = (const float*)d_in[19];
    const float* c3 = (const float*)d_in[20];
    float* outp = (float*)d_out;

    // Workspace: xa 8.4 + xb 8.4 + small + wt 5.24 + I 83.9 ~= 106 MB (<117.5 proven)
    float* ws = (float*)d_ws;
    float* xa = ws;                                    // [8192][<=256] f32
    float* xb = xa + (size_t)8192 * 256;
    float* small = xb + (size_t)8192 * 256;
    float* partial = small;                            // 8192
    unsigned short* wt = (unsigned short*)(small + 16384);     // 5.24 MB max
    unsigned short* Ibuf = wt + (size_t)160 * 2 * 256 * 32;    // 83.9 MB max

    // 1. input normalization -> xa [8192][30]
    norm_kernel<<<(Bz * Vz * 30 + 255) / 256, 256, 0, stream>>>(signal, xa);

    // ---- layer 0: precomputed-I full batch; CBn=1, 40 k-steps, T=128 ----
    expand_wt<30, 128, 40><<<(40 * 128 * 32 + 255) / 256, 256, 0, stream>>>(k0, wt);
    interp_i<30, 1, 8192><<<(8192 * 160 + 255) / 256, 256, 0, stream>>>(
        xa, bc_idx, bc_w, Ibuf, 0);
    gemm_f<1, 128, 2><<<dim3(1, 512), 256, 0, stream>>>(Ibuf, wt, b0, g0, be0, xb, 0);

    // ---- layer 1: round-6 in-kernel-interp kernel (full batch) ----
    expand_wt<128, 128, 160><<<(160 * 128 * 32 + 255) / 256, 256, 0, stream>>>(k1, wt);
    conv_k<128, 128, 160, true><<<dim3(1, 512), 256, 0, stream>>>(
        xb, bc_idx, bc_w, wt, b1, g1, be1, xa);

    // ---- layer 2: precomputed-I per 2 batches; CBn=4, 160 k-steps, T=256, fused ----
    expand_wt<128, 256, 160><<<(160 * 256 * 32 + 255) / 256, 256, 0, stream>>>(k2, wt);
    for (int h = 0; h < 2; ++h) {
        interp_i<128, 4, 4096><<<(4096 * 640 + 255) / 256, 256, 0, stream>>>(
            xa, bc_idx, bc_w, Ibuf, h * 4096);
        gemm_f<4, 256, 4><<<dim3(1, 256), 512, 0, stream>>>(Ibuf, wt, b2, g2, be2, xb, h * 4096);
    }

    // ---- global max pool + fused MLP head ----
    pool1<<<Bz * 8, 256, 0, stream>>>(xb, partial);
    head_k<<<Bz, 256, 0, stream>>>(partial, w1, c1, w2, c2, w3, c3, outp);
}

// Round 11
// 817.417 us; speedup vs baseline: 1.4355x; 1.4355x over previous
//
#include <hip/hip_runtime.h>
#include <hip/hip_bf16.h>
#include <math.h>

// Problem constants
#define Bz 4
#define Vz 2048
#define RA 40   // R*A = 5*8

typedef short bf16x8 __attribute__((ext_vector_type(8)));
typedef float f32x4 __attribute__((ext_vector_type(4)));

__device__ __forceinline__ unsigned fasu(float f){ union{float f;unsigned u;}x;x.f=f;return x.u; }
__device__ __forceinline__ float usaf(unsigned u){ union{unsigned u;float f;}x;x.u=u;return x.f; }

// fp32 -> bf16 RNE (weight split, done once per layer)
__device__ __forceinline__ unsigned short f2bf(float f) {
    unsigned u = fasu(f);
    unsigned r = u + 0x7FFF + ((u >> 16) & 1);
    return (unsigned short)(r >> 16);
}
__device__ __forceinline__ float bf2f(unsigned short h) { return usaf(((unsigned)h) << 16); }

__constant__ float NORM_MEAN_C[30] = {
    -3.7189561e-06f, 0.000286194f, 0.0020740835f, 6.5275993f, -0.0052857199f,
    10.554636f, 0.057773598f, 13.915789f, 0.060970016f, 16.840271f,
    0.0570364f, 19.415283f, 0.044104282f, 21.721455f, 0.11490919f,
    23.64683f, 0.099816084f, 25.365578f, 0.01769533f, 26.861437f,
    0.054662503f, 28.197876f, -0.0024771576f, 29.295244f, 0.039666731f,
    30.319246f, 0.0088442909f, 31.160933f, -0.026727753f, 31.874565f};
__constant__ float NORM_VAR_C[30] = {
    3.3091978e-06f, 0.00016750646f, 0.80988622f, 85135.219f, 1.5621265f,
    222580.2f, 8.812871f, 386912.78f, 10.180468f, 566622.44f,
    9.8600769f, 753158.06f, 7.8372045f, 942701.62f, 30.926426f,
    1117233.0f, 25.045353f, 1285543.9f, 6.3646226f, 1441639.1f,
    12.326629f, 1588653.4f, 6.9686499f, 1714707.9f, 10.755516f,
    1836677.8f, 8.416419f, 1940088.8f, 10.344138f, 2029969.6f};

__device__ __forceinline__ float elu_f(float x) {
    return x > 0.f ? x : expm1f(x);
}

// x0[b,v,c] = (signal - mean[c]) * rsqrt(var[c])
__global__ void norm_kernel(const float* __restrict__ sig, float* __restrict__ x0) {
    int e = blockIdx.x * 256 + threadIdx.x;
    if (e >= Bz * Vz * 30) return;
    int c = e % 30;
    x0[e] = (sig[e] - NORM_MEAN_C[c]) * rsqrtf(NORM_VAR_C[c]);
}

// Weight expand (no rotation; rotations live in M). Split-bf16, fragment-linear:
// per (kb,plane): off = (n>>4)*512 + (kk>>3)*128 + (n&15)*8 + (kk&7)
template <int CROW, int T, int KB>
__global__ void expand_wt(const float* __restrict__ kern, unsigned short* __restrict__ wt) {
    int e = blockIdx.x * 256 + threadIdx.x;
    if (e >= KB * T * 32) return;
    int kb = e / (T * 32);
    int rem = e % (T * 32);
    int n = rem >> 5, kk = rem & 31;
    int ra, c;
    if (CROW == 128) { ra = kb >> 2; c = (kb & 3) * 32 + kk; }
    else             { ra = kb;      c = kk; }
    float v = (c < CROW) ? kern[((size_t)(ra * T + n)) * CROW + c] : 0.f;
    unsigned short hi = f2bf(v);
    unsigned short lo = f2bf(v - bf2f(hi));
    size_t off = ((size_t)kb * 2) * T * 32 + (n >> 4) * 512 + (kk >> 3) * 128 + (n & 15) * 8 + (kk & 7);
    wt[off] = hi;
    wt[off + (size_t)T * 32] = lo;
}

// Fused conv GEMM, round-6 schedule, generalized to NW column-waves:
// threads = 128*NW (2*NW waves: 2 m-waves x NW n-waves, wave tile 64x64),
// BM=128 (16 v x 8 o), BN = 64*NW = T. rows m = b*16384 + v*8 + o, cols n = t.
// Per (r,cblk) group: issue g+1 x-gathers (held in regs, 24*16/CPT regs),
// prefetch idx/w for g+2, 8 MFMA a'-steps (B frags global->VGPR, rotation
// folded into LDS read addr), interp+split -> I[(g+1)&1], ONE barrier.
// Epilogue: elu+bias, AMP argmax over 8 rotations, BN, write [v][T].
template <int CROW, int T, int KB, int NW, bool FUSE>
__global__ __launch_bounds__(128 * NW) void conv_k(const float* __restrict__ x,
                                              const int* __restrict__ bc_idx,
                                              const float* __restrict__ bc_w,
                                              const unsigned short* __restrict__ wt,
                                              const float* __restrict__ bias,
                                              const float* __restrict__ g,
                                              const float* __restrict__ be,
                                              float* __restrict__ xout) {
    constexpr int CB = (CROW == 128) ? 4 : 1;   // c-blocks per ra
    constexpr int G = KB / 8;                   // (r,cblk) groups
    constexpr int CPT = 32 / NW;                // k-elements built per thread
    __shared__ unsigned short Ih[2][4096], Il[2][4096];
    __shared__ float normp[128][NW];
    __shared__ int bo[16];
    const int tid = threadIdx.x;
    const int wid = tid >> 6, lane = tid & 63;
    const int fr = lane & 15, fq = lane >> 4;
    const int fro = fr & 7, frv = fr & 8;
    const int wm = (wid & 1) * 64, wn = (wid >> 1) * 64;
    const int m0 = blockIdx.y * 128;
    const int b = m0 >> 14;                       // batch
    const float* xb_ = x + (size_t)b * Vz * CROW;
    const int* idxb = bc_idx + (size_t)b * Vz * RA * 3;
    const float* wb = bc_w + (size_t)b * Vz * RA * 3;

    // I-build mapping: NW threads per I row; thread covers CPT k's
    const int rloc = tid / NW;                    // 0..127  (v = rloc>>3, a = rloc&7)
    const int cidx = tid % NW;                    // which CPT chunk
    const int aI = rloc & 7;
    const int vglob_b = ((m0 & 16383) >> 3) + (rloc >> 3);
    const int offA = (rloc >> 4) * 512 + (cidx * CPT / 8) * 128 + (rloc & 15) * 8;
    // A-fragment base (lane-const); per a': addr = ibase + mi*512 + rot*8
    const int ibase = (wm >> 4) * 512 + fq * 128 + frv * 8;
    // B-fragment base n-block
    const int nbase = wn >> 4;

    f32x4 acc[4][4] = {};

    auto split_write = [&](const float* vv, int buf) {
#pragma unroll
        for (int half = 0; half < CPT / 8; ++half) {
            unsigned hiw[4], low_[4];
#pragma unroll
            for (int p = 0; p < 4; ++p) {
                float v0 = vv[half * 8 + 2 * p], v1 = vv[half * 8 + 2 * p + 1];
                unsigned u0 = fasu(v0), u1 = fasu(v1);
                unsigned h0 = u0 & 0xFFFF0000u, h1 = u1 & 0xFFFF0000u;
                float l0 = v0 - usaf(h0), l1 = v1 - usaf(h1);
                hiw[p] = (u0 >> 16) | h1;
                low_[p] = (fasu(l0) >> 16) | (fasu(l1) & 0xFFFF0000u);
            }
            *(uint4*)&Ih[buf][offA + half * 128] = make_uint4(hiw[0], hiw[1], hiw[2], hiw[3]);
            *(uint4*)&Il[buf][offA + half * 128] = make_uint4(low_[0], low_[1], low_[2], low_[3]);
        }
    };

    // ---- prologue: build I for group 0; prefetch idx/w for group 1 ----
    int i_n0 = 0, i_n1 = 0, i_n2 = 0; float w_n0 = 0.f, w_n1 = 0.f, w_n2 = 0.f;
    {
        const int gi = (vglob_b * RA + aI) * 3;   // g=0 -> r=0
        int a0 = idxb[gi], a1 = idxb[gi + 1], a2 = idxb[gi + 2];
        float b0_ = wb[gi], b1_ = wb[gi + 1], b2_ = wb[gi + 2];
        float vv[CPT];
        const int cs0 = cidx * CPT;               // g=0 -> cb=0
        if (CROW == 128) {
            const float4* q0 = (const float4*)(xb_ + (size_t)a0 * CROW + cs0);
            const float4* q1 = (const float4*)(xb_ + (size_t)a1 * CROW + cs0);
            const float4* q2 = (const float4*)(xb_ + (size_t)a2 * CROW + cs0);
#pragma unroll
            for (int qq = 0; qq < CPT / 4; ++qq) {
                float4 a4 = q0[qq], b4 = q1[qq], c4 = q2[qq];
                vv[qq * 4 + 0] = b0_ * a4.x + b1_ * b4.x + b2_ * c4.x;
                vv[qq * 4 + 1] = b0_ * a4.y + b1_ * b4.y + b2_ * c4.y;
                vv[qq * 4 + 2] = b0_ * a4.z + b1_ * b4.z + b2_ * c4.z;
                vv[qq * 4 + 3] = b0_ * a4.w + b1_ * b4.w + b2_ * c4.w;
            }
        } else {
            const float* q0 = xb_ + (size_t)a0 * CROW;
            const float* q1 = xb_ + (size_t)a1 * CROW;
            const float* q2 = xb_ + (size_t)a2 * CROW;
#pragma unroll
            for (int j = 0; j < CPT; ++j) {
                int c = cs0 + j;
                vv[j] = (c < CROW) ? (b0_ * q0[c] + b1_ * q1[c] + b2_ * q2[c]) : 0.f;
            }
        }
        split_write(vv, 0);
        if (G > 1) {
            const int rn = 1 / CB;
            const int gi2 = (vglob_b * RA + rn * 8 + aI) * 3;
            i_n0 = idxb[gi2]; i_n1 = idxb[gi2 + 1]; i_n2 = idxb[gi2 + 2];
            w_n0 = wb[gi2];   w_n1 = wb[gi2 + 1];   w_n2 = wb[gi2 + 2];
        }
    }
    __syncthreads();

    for (int gidx = 0; gidx < G; ++gidx) {
        const bool hn = (gidx + 1 < G);
        // save next-group idx/w before the g+2 prefetch overwrites them
        const int ni0 = i_n0, ni1 = i_n1, ni2 = i_n2;
        const float nw0 = w_n0, nw1 = w_n1, nw2 = w_n2;
        const int cs_n = ((gidx + 1) % CB) * 32 + cidx * CPT;

        // ---- 1. issue x-gathers for group g+1 (held in regs through MFMAs) ----
        float4 qr0[CPT / 4], qr1[CPT / 4], qr2[CPT / 4];
        float gq0[CPT], gq1[CPT], gq2[CPT];
        if (hn) {
            if (CROW == 128) {
                const float4* q0 = (const float4*)(xb_ + (size_t)ni0 * CROW + cs_n);
                const float4* q1 = (const float4*)(xb_ + (size_t)ni1 * CROW + cs_n);
                const float4* q2 = (const float4*)(xb_ + (size_t)ni2 * CROW + cs_n);
#pragma unroll
                for (int qq = 0; qq < CPT / 4; ++qq) { qr0[qq] = q0[qq]; qr1[qq] = q1[qq]; qr2[qq] = q2[qq]; }
            } else {
                const float* q0 = xb_ + (size_t)ni0 * CROW;
                const float* q1 = xb_ + (size_t)ni1 * CROW;
                const float* q2 = xb_ + (size_t)ni2 * CROW;
#pragma unroll
                for (int j = 0; j < CPT; ++j) {
                    int c = cs_n + j;
                    bool ok = (c < CROW);
                    gq0[j] = ok ? q0[c] : 0.f;
                    gq1[j] = ok ? q1[c] : 0.f;
                    gq2[j] = ok ? q2[c] : 0.f;
                }
            }
        }
        // ---- 2. prefetch idx/w for group g+2 ----
        if (gidx + 2 < G) {
            const int rn = (gidx + 2) / CB;
            const int gi = (vglob_b * RA + rn * 8 + aI) * 3;
            i_n0 = idxb[gi]; i_n1 = idxb[gi + 1]; i_n2 = idxb[gi + 2];
            w_n0 = wb[gi];   w_n1 = wb[gi + 1];   w_n2 = wb[gi + 2];
        }

        // ---- 3. 8 MFMA steps; B fragments straight from global (L2) ----
        const int r8 = (gidx / CB) * 8;
        const int cbg = gidx % CB;
        const int ibuf = gidx & 1;
#pragma unroll
        for (int ap = 0; ap < 8; ++ap) {
            const int kb = (CROW == 128) ? ((r8 + ap) * 4 + cbg) : (r8 + ap);
            const unsigned short* bb = wt + ((size_t)kb * 2) * (T * 32) +
                                       (size_t)nbase * 512 + lane * 8;
            bf16x8 bh[4], bl[4];
#pragma unroll
            for (int nj = 0; nj < 4; ++nj) {
                bh[nj] = *(const bf16x8*)(bb + nj * 512);
                bl[nj] = *(const bf16x8*)(bb + (size_t)T * 32 + nj * 512);
            }
            const int rot = (ap + fro) & 7;
            bf16x8 ah[4], al[4];
#pragma unroll
            for (int mi = 0; mi < 4; ++mi) {
                const int ad = ibase + mi * 512 + rot * 8;
                ah[mi] = *(const bf16x8*)&Ih[ibuf][ad];
                al[mi] = *(const bf16x8*)&Il[ibuf][ad];
            }
#pragma unroll
            for (int mi = 0; mi < 4; ++mi)
#pragma unroll
                for (int nj = 0; nj < 4; ++nj) {
                    acc[mi][nj] = __builtin_amdgcn_mfma_f32_16x16x32_bf16(ah[mi], bh[nj], acc[mi][nj], 0, 0, 0);
                    acc[mi][nj] = __builtin_amdgcn_mfma_f32_16x16x32_bf16(ah[mi], bl[nj], acc[mi][nj], 0, 0, 0);
                    acc[mi][nj] = __builtin_amdgcn_mfma_f32_16x16x32_bf16(al[mi], bh[nj], acc[mi][nj], 0, 0, 0);
                }
        }

        // ---- 4. interp + split + write I for group g+1 ----
        if (hn) {
            float vv[CPT];
            if (CROW == 128) {
#pragma unroll
                for (int qq = 0; qq < CPT / 4; ++qq) {
                    float4 a4 = qr0[qq], b4 = qr1[qq], c4 = qr2[qq];
                    vv[qq * 4 + 0] = nw0 * a4.x + nw1 * b4.x + nw2 * c4.x;
                    vv[qq * 4 + 1] = nw0 * a4.y + nw1 * b4.y + nw2 * c4.y;
                    vv[qq * 4 + 2] = nw0 * a4.z + nw1 * b4.z + nw2 * c4.z;
                    vv[qq * 4 + 3] = nw0 * a4.w + nw1 * b4.w + nw2 * c4.w;
                }
            } else {
#pragma unroll
                for (int j = 0; j < CPT; ++j)
                    vv[j] = nw0 * gq0[j] + nw1 * gq1[j] + nw2 * gq2[j];
            }
            split_write(vv, (gidx + 1) & 1);
        }
        __syncthreads();
    }

    if (FUSE) {
        // elu + bias, per-row squared norms, argmax over 8 rotations, BN, write
        float ss[4][4];
#pragma unroll
        for (int mi = 0; mi < 4; ++mi)
#pragma unroll
            for (int r = 0; r < 4; ++r) ss[mi][r] = 0.f;
#pragma unroll
        for (int mi = 0; mi < 4; ++mi)
#pragma unroll
            for (int nj = 0; nj < 4; ++nj)
#pragma unroll
                for (int r = 0; r < 4; ++r) {
                    float val = elu_f(acc[mi][nj][r] + bias[wn + nj * 16 + fr]);
                    acc[mi][nj][r] = val;
                    ss[mi][r] += val * val;
                }
#pragma unroll
        for (int mi = 0; mi < 4; ++mi)
#pragma unroll
            for (int r = 0; r < 4; ++r) {
                float s = ss[mi][r];
                s += __shfl_xor(s, 1); s += __shfl_xor(s, 2);
                s += __shfl_xor(s, 4); s += __shfl_xor(s, 8);
                if (fr == 0) normp[wm + mi * 16 + fq * 4 + r][wn >> 6] = s;
            }
        __syncthreads();
        if (tid < 16) {
            float best = -1.f; int bsel = 0;
#pragma unroll
            for (int oo = 0; oo < 8; ++oo) {
                float tot = 0.f;
#pragma unroll
                for (int wq = 0; wq < NW; ++wq) tot += normp[tid * 8 + oo][wq];
                if (tot > best) { best = tot; bsel = oo; }   // first max wins
            }
            bo[tid] = bsel;
        }
        __syncthreads();
        const float rsbn = rsqrtf(1.001f);
#pragma unroll
        for (int mi = 0; mi < 4; ++mi)
#pragma unroll
            for (int r = 0; r < 4; ++r) {
                int row = wm + mi * 16 + fq * 4 + r;
                if ((row & 7) == bo[row >> 3]) {
                    int vg = (m0 >> 3) + (row >> 3);   // global vertex 0..8191
#pragma unroll
                    for (int nj = 0; nj < 4; ++nj) {
                        int t = wn + nj * 16 + fr;
                        xout[(size_t)vg * T + t] = acc[mi][nj][r] * g[t] * rsbn + be[t];
                    }
                }
            }
    }
}

// Global max pool stage 1. x: [B][V][256] -> partial [B*8][256]
__global__ void pool1(const float* __restrict__ x, float* __restrict__ partial) {
    int b = blockIdx.x >> 3, ch = blockIdx.x & 7, t = threadIdx.x;
    float m = -INFINITY;
    for (int i = 0; i < 256; ++i) {
        int v = ch * 256 + i;
        m = fmaxf(m, x[((size_t)b * Vz + v) * 256 + t]);
    }
    partial[(size_t)blockIdx.x * 256 + t] = m;
}

// Fused head: finish max-pool + 3-layer MLP. One block per batch.
__global__ __launch_bounds__(256) void head_k(const float* __restrict__ partial,
                                              const float* __restrict__ w1, const float* __restrict__ c1,
                                              const float* __restrict__ w2, const float* __restrict__ c2,
                                              const float* __restrict__ w3, const float* __restrict__ c3,
                                              float* __restrict__ outp) {
    __shared__ float p[256], h1s[512], h2s[256];
    const int b = blockIdx.x, tid = threadIdx.x;
    float m = -INFINITY;
#pragma unroll
    for (int ch = 0; ch < 8; ++ch)
        m = fmaxf(m, partial[((size_t)b * 8 + ch) * 256 + tid]);
    p[tid] = m;
    __syncthreads();
#pragma unroll
    for (int rep = 0; rep < 2; ++rep) {
        int n = rep * 256 + tid;
        float s = c1[n];
        for (int k = 0; k < 256; ++k) s += p[k] * w1[k * 512 + n];
        h1s[n] = elu_f(s);
    }
    __syncthreads();
    {
        float s = c2[tid];
        for (int k = 0; k < 512; ++k) s += h1s[k] * w2[k * 256 + tid];
        h2s[tid] = elu_f(s);
    }
    __syncthreads();
    if (tid < 40) {
        float s = c3[tid];
        for (int k = 0; k < 256; ++k) s += h2s[k] * w3[k * 40 + tid];
        outp[b * 40 + tid] = s;
    }
}

extern "C" void kernel_launch(void* const* d_in, const int* in_sizes, int n_in,
                              void* d_out, int out_size, void* d_ws, size_t ws_size,
                              hipStream_t stream) {
    const float* signal = (const float*)d_in[0];
    const int* bc_idx = (const int*)d_in[1];
    const float* bc_w = (const float*)d_in[2];
    const float* k0 = (const float*)d_in[3];
    const float* b0 = (const float*)d_in[4];
    const float* g0 = (const float*)d_in[5];
    const float* be0 = (const float*)d_in[6];
    const float* k1 = (const float*)d_in[7];
    const float* b1 = (const float*)d_in[8];
    const float* g1 = (const float*)d_in[9];
    const float* be1 = (const float*)d_in[10];
    const float* k2 = (const float*)d_in[11];
    const float* b2 = (const float*)d_in[12];
    const float* g2 = (const float*)d_in[13];
    const float* be2 = (const float*)d_in[14];
    const float* w1 = (const float*)d_in[15];
    const float* c1 = (const float*)d_in[16];
    const float* w2 = (const float*)d_in[17];
    const float* c2 = (const float*)d_in[18];
    const float* w3 = (const float*)d_in[19];
    const float* c3 = (const float*)d_in[20];
    float* outp = (float*)d_out;

    // Workspace: xa 8.4 + xb 8.4 + small + wt 5.24 MB ~= 22 MB
    float* ws = (float*)d_ws;
    float* xa = ws;                                    // [8192][<=256] f32
    float* xb = xa + (size_t)8192 * 256;
    float* small = xb + (size_t)8192 * 256;
    float* partial = small;                            // 8192
    unsigned short* wt = (unsigned short*)(small + 16384);  // max 160*2*256*32 u16 = 5.24 MB

    // 1. input normalization -> xa [8192][30]
    norm_kernel<<<(Bz * Vz * 30 + 255) / 256, 256, 0, stream>>>(signal, xa);

    // ---- layer 0: CROW=30 (KB=40), T=128, NW=2, fused AMP ----
    expand_wt<30, 128, 40><<<(40 * 128 * 32 + 255) / 256, 256, 0, stream>>>(k0, wt);
    conv_k<30, 128, 40, 2, true><<<dim3(1, 512), 256, 0, stream>>>(
        xa, bc_idx, bc_w, wt, b0, g0, be0, xb);

    // ---- layer 1: CROW=128 (KB=160), T=128, NW=2, fused AMP ----
    expand_wt<128, 128, 160><<<(160 * 128 * 32 + 255) / 256, 256, 0, stream>>>(k1, wt);
    conv_k<128, 128, 160, 2, true><<<dim3(1, 512), 256, 0, stream>>>(
        xb, bc_idx, bc_w, wt, b1, g1, be1, xa);

    // ---- layer 2: CROW=128 (KB=160), T=256, NW=4 (512 thr), fused AMP ----
    expand_wt<128, 256, 160><<<(160 * 256 * 32 + 255) / 256, 256, 0, stream>>>(k2, wt);
    conv_k<128, 256, 160, 4, true><<<dim3(1, 512), 512, 0, stream>>>(
        xa, bc_idx, bc_w, wt, b2, g2, be2, xb);

    // ---- global max pool + fused MLP head ----
    pool1<<<Bz * 8, 256, 0, stream>>>(xb, partial);
    head_k<<<Bz, 256, 0, stream>>>(partial, w1, c1, w2, c2, w3, c3, outp);
}